// Round 6
// baseline (169.727 us; speedup 1.0000x reference)
//
#include <hip/hip_runtime.h>
#include <math.h>

// ---- geometry ----
// Grid 50^3, coords shifted +1 -> occupy [1,50]. Dense key = (z*54+y)*64+x.
// z can reach 57 in halo probes (8-deep bricks) -> z-dim 58.
#define GY 54
#define ZD 58
#define NROWS (ZD*GY*64)      // 200448 keys

// brick 8x4x8 = 256 output voxels per block; halo 10x6x10 = 600 rows
#define HX 10
#define HY 6
#define HXY 60
#define NH 600
#define NBX 7                 // ceil(50/8)
#define NBY 13                // ceil(50/4)
#define NBZ 7                 // ceil(50/8)
#define NBRICK (NBX*NBY*NBZ)  // 637
#define SLAB 80               // ceil(637/8) bricks per XCD

#define LDK 72                // LDS row stride in bf16 (144 B = 9*16B)

typedef __bf16  bf16x8 __attribute__((ext_vector_type(8)));
typedef float  f32x16 __attribute__((ext_vector_type(16)));

// ---- fused prep: maps + reverse keys + W -> Wt (bf16, [27][cout][cin]) ----
// No memset needed: conv validates every map entry against ikey/okey.
__global__ void prep_kernel(const float* __restrict__ ipos, int n,
                            const float* __restrict__ opos, int m,
                            const float* __restrict__ vsp,
                            const float* __restrict__ W,
                            int* __restrict__ imap, int* __restrict__ ikey,
                            int* __restrict__ omap, int* __restrict__ okey,
                            __bf16* __restrict__ Wt) {
    int i = blockIdx.x * 256 + threadIdx.x;
    float vs = vsp[0];
    if (i < n) {
        int x = (int)floorf(ipos[3*i+0] / vs) + 1;
        int y = (int)floorf(ipos[3*i+1] / vs) + 1;
        int z = (int)floorf(ipos[3*i+2] / vs) + 1;
        int key = (z * GY + y) * 64 + x;
        ikey[i] = key;
        imap[key] = i;
    } else if (i < n + m) {
        int j = i - n;
        int x = (int)floorf(opos[3*j+0] / vs) + 1;
        int y = (int)floorf(opos[3*j+1] / vs) + 1;
        int z = (int)floorf(opos[3*j+2] / vs) + 1;
        int key = (z * GY + y) * 64 + x;
        okey[j] = key;
        omap[key] = j;
    } else if (i < n + m + 27*64*64) {
        int k  = i - n - m;
        int t  = k >> 12;
        int r  = k & 4095;
        int ci = r >> 6;
        int co = r & 63;
        Wt[(t << 12) + (co << 6) + ci] = (__bf16)W[k];
    }
}

__global__ __launch_bounds__(256, 1) void conv_kernel(
    const float* __restrict__ feats,    // [N,64] fp32
    const __bf16* __restrict__ Wt,      // [27][64cout][64cin]
    const float* __restrict__ bias,     // [64]
    const int*   __restrict__ imap,
    const int*   __restrict__ ikey,
    const int*   __restrict__ omap,
    const int*   __restrict__ okey,
    float*       __restrict__ out,      // [M,64]
    int N, int M)
{
    __shared__ __align__(16) __bf16 halo[NH * LDK];    // 86400 B
    __shared__ __align__(16) __bf16 Bld[2][64 * LDK];  // 18432 B
    __shared__ int ridx[NH];                           //  2400 B
    __shared__ int obuf[256];                          //  1024 B

    const int tid = threadIdx.x;

    // XCD slab swizzle
    int q = (blockIdx.x & 7) * SLAB + (blockIdx.x >> 3);
    if (q >= NBRICK) return;   // whole block exits together (pre-barrier)
    const int bx = q % NBX;
    int rem = q / NBX;
    const int by = rem % NBY;
    const int bz = rem / NBY;

    // ---- W staging roles: 512 float4 tasks (64 rows x 8 chunks), 2/thread ----
    const int wr0 = tid >> 3;          // rows 0..31
    const int wr1 = 32 + wr0;          // rows 32..63
    const int wc  = tid & 7;

    // tap 0 -> regs -> buf0; prefetch tap 1 into regs
    float4 wreg0 = *(const float4*)(Wt + wr0 * 64 + wc * 8);
    float4 wreg1 = *(const float4*)(Wt + wr1 * 64 + wc * 8);
    *(float4*)(&Bld[0][wr0 * LDK + wc * 8]) = wreg0;
    *(float4*)(&Bld[0][wr1 * LDK + wc * 8]) = wreg1;
    wreg0 = *(const float4*)(Wt + 4096 + wr0 * 64 + wc * 8);
    wreg1 = *(const float4*)(Wt + 4096 + wr1 * 64 + wc * 8);

    // ---- phase A: resolve halo row indices (validated) + output rows ----
    #pragma unroll
    for (int it = 0; it < 3; ++it) {
        int r = it * 256 + tid;
        if (r < NH) {
            int xs = r % HX;
            int t2 = r / HX;
            int ys = t2 % HY;
            int zs = t2 / HY;
            int key = ((bz*8 + zs) * GY + (by*4 + ys)) * 64 + (bx*8 + xs);
            int idx = imap[key];
            int c = min(max(idx, 0), N - 1);
            ridx[r] = (idx >= 0 && idx < N && ikey[c] == key) ? idx : -1;
        }
    }
    {
        int x = tid & 7, y = (tid >> 3) & 3, z = tid >> 5;
        int key = ((bz*8 + z + 1) * GY + (by*4 + y + 1)) * 64 + (bx*8 + x + 1);
        int o = omap[key];
        int c = min(max(o, 0), M - 1);
        obuf[tid] = (o >= 0 && o < M && okey[c] == key) ? o : -1;
    }
    __syncthreads();   // ridx visible for halo fill

    // ---- phase B: halo fill (gather fp32 rows, convert to bf16) ----
    #pragma unroll
    for (int it = 0; it < 19; ++it) {
        int task = it * 256 + tid;
        if (task < NH * 8) {
            int r = task >> 3, c = task & 7;
            int idx = ridx[r];
            bf16x8 v;
            if (idx >= 0) {
                const float4* s = (const float4*)(feats + (size_t)idx * 64 + c * 8);
                float4 f0 = s[0], f1 = s[1];
                v[0]=(__bf16)f0.x; v[1]=(__bf16)f0.y; v[2]=(__bf16)f0.z; v[3]=(__bf16)f0.w;
                v[4]=(__bf16)f1.x; v[5]=(__bf16)f1.y; v[6]=(__bf16)f1.z; v[7]=(__bf16)f1.w;
            } else {
                #pragma unroll
                for (int j = 0; j < 8; ++j) v[j] = (__bf16)0.f;
            }
            *(bf16x8*)(halo + r * LDK + c * 8) = v;
        }
    }

    // compute roles: wave owns z-slices {2w, 2w+1} (2 m-tiles) x both n-tiles
    const int wave  = tid >> 6;
    const int lane  = tid & 63;
    const int lrow  = lane & 31;
    const int halfk = lane >> 5;
    const int xv = lrow & 7, yv = lrow >> 3;
    const __bf16* A0base = halo + ((2*wave + 1) * HXY + (yv + 1) * HX + (xv + 1)) * LDK
                                + halfk * 8;
    const int Bb0 = lrow * LDK + halfk * 8;
    const int Bb1 = Bb0 + 32 * LDK;

    f32x16 acc00, acc01, acc10, acc11;
    #pragma unroll
    for (int i = 0; i < 16; ++i) { acc00[i]=0.f; acc01[i]=0.f; acc10[i]=0.f; acc11[i]=0.f; }

    __syncthreads();   // halo + obuf + Bld[0] visible

    #pragma unroll 1
    for (int t = 0; t < 27; ++t) {
        // write tap t+1 (in regs) into the alternate buffer
        if (t < 26) {
            __bf16* nb = &Bld[(t + 1) & 1][0];
            *(float4*)(nb + wr0 * LDK + wc * 8) = wreg0;
            *(float4*)(nb + wr1 * LDK + wc * 8) = wreg1;
        }
        // issue global loads for tap t+2
        if (t < 25) {
            const __bf16* wp = Wt + ((size_t)(t + 2) << 12);
            wreg0 = *(const float4*)(wp + wr0 * 64 + wc * 8);
            wreg1 = *(const float4*)(wp + wr1 * 64 + wc * 8);
        }

        const int dx = t % 3 - 1;
        const int dy = (t / 3) % 3 - 1;
        const int dz = t / 9 - 1;
        const __bf16* Ab0 = A0base + (dz * HXY + dy * HX + dx) * LDK;
        const __bf16* Ab1 = Ab0 + HXY * LDK;
        const __bf16* Bbuf = &Bld[t & 1][0];

        #pragma unroll
        for (int kc = 0; kc < 4; ++kc) {
            bf16x8 a0 = *(const bf16x8*)(Ab0 + kc * 16);
            bf16x8 a1 = *(const bf16x8*)(Ab1 + kc * 16);
            bf16x8 b0 = *(const bf16x8*)(Bbuf + Bb0 + kc * 16);
            bf16x8 b1 = *(const bf16x8*)(Bbuf + Bb1 + kc * 16);
            acc00 = __builtin_amdgcn_mfma_f32_32x32x16_bf16(a0, b0, acc00, 0, 0, 0);
            acc01 = __builtin_amdgcn_mfma_f32_32x32x16_bf16(a0, b1, acc01, 0, 0, 0);
            acc10 = __builtin_amdgcn_mfma_f32_32x32x16_bf16(a1, b0, acc10, 0, 0, 0);
            acc11 = __builtin_amdgcn_mfma_f32_32x32x16_bf16(a1, b1, acc11, 0, 0, 0);
        }
        __syncthreads();   // reads of Bld[t&1] done before next iter overwrites
    }

    // ---- epilogue: C/D layout col=lane&31, row=(reg&3)+8*(reg>>2)+4*(lane>>5) ----
    const int col0 = lrow, col1 = 32 + lrow;
    const float bv0 = bias[col0], bv1 = bias[col1];
    #pragma unroll
    for (int r = 0; r < 16; ++r) {
        int mrow = (r & 3) + 8 * (r >> 2) + 4 * halfk;   // 0..31 within tile
        int v0 = (2*wave) * 32 + mrow;
        int o0 = obuf[v0];
        int o1 = obuf[v0 + 32];
        if (o0 >= 0) {
            out[(size_t)o0 * 64 + col0] = acc00[r] + bv0;
            out[(size_t)o0 * 64 + col1] = acc01[r] + bv1;
        }
        if (o1 >= 0) {
            out[(size_t)o1 * 64 + col0] = acc10[r] + bv0;
            out[(size_t)o1 * 64 + col1] = acc11[r] + bv1;
        }
    }
}

extern "C" void kernel_launch(void* const* d_in, const int* in_sizes, int n_in,
                              void* d_out, int out_size, void* d_ws, size_t ws_size,
                              hipStream_t stream) {
    const float* feats = (const float*)d_in[0];
    const float* ipos  = (const float*)d_in[1];
    const float* opos  = (const float*)d_in[2];
    const float* vsp   = (const float*)d_in[3];
    const float* W     = (const float*)d_in[4];
    const float* bias  = (const float*)d_in[5];

    int N = in_sizes[0] / 64;
    int M = out_size / 64;

    // workspace: imap | omap | ikey | okey | Wt   (no clearing required)
    int*    imap = (int*)d_ws;
    int*    omap = imap + NROWS;
    int*    ikey = omap + NROWS;
    int*    okey = ikey + N;
    __bf16* Wt   = (__bf16*)(okey + M);

    int total = N + M + 27*64*64;
    prep_kernel<<<(total + 255) / 256, 256, 0, stream>>>(ipos, N, opos, M, vsp, W,
                                                         imap, ikey, omap, okey, Wt);
    conv_kernel<<<8 * SLAB, 256, 0, stream>>>(feats, Wt, bias, imap, ikey, omap, okey,
                                              (float*)d_out, N, M);
}

// Round 7
// 145.062 us; speedup vs baseline: 1.1700x; 1.1700x over previous
//
#include <hip/hip_runtime.h>
#include <math.h>

// ---- geometry ----
// Grid 50^3, coords shifted +1 -> occupy [1,50]. Dense key = (z*54+y)*64+x.
#define GY 54
#define NROWS (54*54*64)      // 186624 keys

// brick 8x4x4 = 128 output voxels per block; halo 10x6x6 = 360 rows
#define HX 10
#define HY 6
#define HXY 60
#define NH 360
#define NBX 7                 // ceil(50/8)
#define NBY 13
#define NBRICK (7*13*13)      // 1183
#define SLAB 148              // ceil(1183/8) bricks per XCD

#define LDK 72                // LDS row stride in bf16 (144 B = 9*16B)

typedef __bf16  bf16x8 __attribute__((ext_vector_type(8)));
typedef float  f32x16 __attribute__((ext_vector_type(16)));

// ---- fused prep: maps + reverse keys + W -> Wt (bf16, [27][cout][cin]) ----
// No memset needed: conv validates every map entry against ikey/okey.
__global__ void prep_kernel(const float* __restrict__ ipos, int n,
                            const float* __restrict__ opos, int m,
                            const float* __restrict__ vsp,
                            const float* __restrict__ W,
                            int* __restrict__ imap, int* __restrict__ ikey,
                            int* __restrict__ omap, int* __restrict__ okey,
                            __bf16* __restrict__ Wt) {
    int i = blockIdx.x * 256 + threadIdx.x;
    float vs = vsp[0];
    if (i < n) {
        int x = (int)floorf(ipos[3*i+0] / vs) + 1;
        int y = (int)floorf(ipos[3*i+1] / vs) + 1;
        int z = (int)floorf(ipos[3*i+2] / vs) + 1;
        int key = (z * GY + y) * 64 + x;
        ikey[i] = key;
        imap[key] = i;
    } else if (i < n + m) {
        int j = i - n;
        int x = (int)floorf(opos[3*j+0] / vs) + 1;
        int y = (int)floorf(opos[3*j+1] / vs) + 1;
        int z = (int)floorf(opos[3*j+2] / vs) + 1;
        int key = (z * GY + y) * 64 + x;
        okey[j] = key;
        omap[key] = j;
    } else if (i < n + m + 27*64*64) {
        int k  = i - n - m;
        int t  = k >> 12;
        int r  = k & 4095;
        int ci = r >> 6;
        int co = r & 63;
        Wt[(t << 12) + (co << 6) + ci] = (__bf16)W[k];
    }
}

__global__ __launch_bounds__(256, 2) void conv_kernel(
    const float* __restrict__ feats,    // [N,64] fp32
    const __bf16* __restrict__ Wt,      // [27][64cout][64cin]
    const float* __restrict__ bias,     // [64]
    const int*   __restrict__ imap,
    const int*   __restrict__ ikey,
    const int*   __restrict__ omap,
    const int*   __restrict__ okey,
    float*       __restrict__ out,      // [M,64]
    int N, int M)
{
    __shared__ __align__(16) __bf16 halo[NH * LDK];    // 51840 B
    __shared__ __align__(16) __bf16 Bld[2][64 * LDK];  // 18432 B
    __shared__ int ridx[NH];                           //  1440 B
    __shared__ int obuf[128];                          //   512 B

    const int tid = threadIdx.x;

    // XCD slab swizzle
    int q = (blockIdx.x & 7) * SLAB + (blockIdx.x >> 3);
    if (q >= NBRICK) return;   // whole block exits together (pre-barrier)
    const int bx = q % NBX;
    int rem = q / NBX;
    const int by = rem % NBY;
    const int bz = rem / NBY;

    // ---- W staging roles: 512 float4 tasks (64 rows x 8 chunks), 2/thread ----
    const int wr0 = tid >> 3;          // rows 0..31
    const int wr1 = 32 + wr0;          // rows 32..63
    const int wc  = tid & 7;

    // tap 0 -> regs -> buf0; prefetch tap 1 into regs
    float4 wreg0 = *(const float4*)(Wt + wr0 * 64 + wc * 8);
    float4 wreg1 = *(const float4*)(Wt + wr1 * 64 + wc * 8);
    *(float4*)(&Bld[0][wr0 * LDK + wc * 8]) = wreg0;
    *(float4*)(&Bld[0][wr1 * LDK + wc * 8]) = wreg1;
    wreg0 = *(const float4*)(Wt + 4096 + wr0 * 64 + wc * 8);
    wreg1 = *(const float4*)(Wt + 4096 + wr1 * 64 + wc * 8);

    // ---- phase A: resolve halo row indices (validated) + output rows ----
    #pragma unroll
    for (int it = 0; it < 2; ++it) {
        int r = it * 256 + tid;
        if (r < NH) {
            int xs = r % HX;
            int t2 = r / HX;
            int ys = t2 % HY;
            int zs = t2 / HY;
            int key = ((bz*4 + zs) * GY + (by*4 + ys)) * 64 + (bx*8 + xs);
            int idx = imap[key];
            int c = min(max(idx, 0), N - 1);
            ridx[r] = (idx >= 0 && idx < N && ikey[c] == key) ? idx : -1;
        }
    }
    if (tid < 128) {
        int x = tid & 7, y = (tid >> 3) & 3, z = tid >> 5;
        int key = ((bz*4 + z + 1) * GY + (by*4 + y + 1)) * 64 + (bx*8 + x + 1);
        int o = omap[key];
        int c = min(max(o, 0), M - 1);
        obuf[tid] = (o >= 0 && o < M && okey[c] == key) ? o : -1;
    }
    __syncthreads();   // ridx visible for halo fill

    // ---- phase B: halo fill (gather fp32 rows, convert to bf16) ----
    #pragma unroll
    for (int it = 0; it < 12; ++it) {
        int task = it * 256 + tid;
        if (task < NH * 8) {
            int r = task >> 3, c = task & 7;
            int idx = ridx[r];
            bf16x8 v;
            if (idx >= 0) {
                const float4* s = (const float4*)(feats + (size_t)idx * 64 + c * 8);
                float4 f0 = s[0], f1 = s[1];
                v[0]=(__bf16)f0.x; v[1]=(__bf16)f0.y; v[2]=(__bf16)f0.z; v[3]=(__bf16)f0.w;
                v[4]=(__bf16)f1.x; v[5]=(__bf16)f1.y; v[6]=(__bf16)f1.z; v[7]=(__bf16)f1.w;
            } else {
                #pragma unroll
                for (int j = 0; j < 8; ++j) v[j] = (__bf16)0.f;
            }
            *(bf16x8*)(halo + r * LDK + c * 8) = v;
        }
    }

    // compute roles: wave = z-slice (1 m-tile), both n-tiles (all 64 couts)
    const int wave  = tid >> 6;
    const int lane  = tid & 63;
    const int lrow  = lane & 31;
    const int halfk = lane >> 5;
    const int xv = lrow & 7, yv = (lrow >> 3) & 3;
    const __bf16* Abase = halo + ((wave + 1) * HXY + (yv + 1) * HX + (xv + 1)) * LDK
                               + halfk * 8;
    const int Bb0 = lrow * LDK + halfk * 8;
    const int Bb1 = Bb0 + 32 * LDK;

    f32x16 acc0, acc1;
    #pragma unroll
    for (int i = 0; i < 16; ++i) { acc0[i] = 0.f; acc1[i] = 0.f; }

    __syncthreads();   // halo + obuf + Bld[0] visible

    // preload tap-0 A fragments (halo is static from here on: no barrier dep)
    bf16x8 acur[4];
    {
        const __bf16* Ab = Abase + (-1 * HXY - 1 * HX - 1) * LDK;  // tap 0: d=(-1,-1,-1)
        #pragma unroll
        for (int kc = 0; kc < 4; ++kc) acur[kc] = *(const bf16x8*)(Ab + kc * 16);
    }

    // fully unrolled tap loop: constant offsets, 27x scheduling window
    #pragma unroll
    for (int t = 0; t < 27; ++t) {
        // stage B(t+1) (regs -> alternate buffer); visible after end-of-iter barrier
        if (t < 26) {
            __bf16* nb = &Bld[(t + 1) & 1][0];
            *(float4*)(nb + wr0 * LDK + wc * 8) = wreg0;
            *(float4*)(nb + wr1 * LDK + wc * 8) = wreg1;
        }
        // issue W global loads for tap t+2
        if (t < 25) {
            const __bf16* wp = Wt + ((size_t)(t + 2) << 12);
            wreg0 = *(const float4*)(wp + wr0 * 64 + wc * 8);
            wreg1 = *(const float4*)(wp + wr1 * 64 + wc * 8);
        }

        const __bf16* Bbuf = &Bld[t & 1][0];
        bf16x8 b0[4], b1[4];
        #pragma unroll
        for (int kc = 0; kc < 4; ++kc) {
            b0[kc] = *(const bf16x8*)(Bbuf + Bb0 + kc * 16);
            b1[kc] = *(const bf16x8*)(Bbuf + Bb1 + kc * 16);
        }

        // prefetch A(t+1) during this tap's MFMAs (no barrier dependency)
        bf16x8 anext[4];
        if (t < 26) {
            const int tn = t + 1;
            const int dx = tn % 3 - 1;
            const int dy = (tn / 3) % 3 - 1;
            const int dz = tn / 9 - 1;
            const __bf16* An = Abase + (dz * HXY + dy * HX + dx) * LDK;
            #pragma unroll
            for (int kc = 0; kc < 4; ++kc) anext[kc] = *(const bf16x8*)(An + kc * 16);
        }

        #pragma unroll
        for (int kc = 0; kc < 4; ++kc) {
            acc0 = __builtin_amdgcn_mfma_f32_32x32x16_bf16(acur[kc], b0[kc], acc0, 0, 0, 0);
            acc1 = __builtin_amdgcn_mfma_f32_32x32x16_bf16(acur[kc], b1[kc], acc1, 0, 0, 0);
        }

        if (t < 26) {
            #pragma unroll
            for (int kc = 0; kc < 4; ++kc) acur[kc] = anext[kc];
        }
        __syncthreads();   // reads of Bld[t&1] done before next iter overwrites
    }

    // ---- epilogue: C/D layout col=lane&31, row=(reg&3)+8*(reg>>2)+4*(lane>>5) ----
    const int col0 = lrow, col1 = 32 + lrow;
    const float bv0 = bias[col0], bv1 = bias[col1];
    #pragma unroll
    for (int r = 0; r < 16; ++r) {
        int mrow = (r & 3) + 8 * (r >> 2) + 4 * halfk;
        int orow = obuf[wave * 32 + mrow];
        if (orow >= 0) {
            out[(size_t)orow * 64 + col0] = acc0[r] + bv0;
            out[(size_t)orow * 64 + col1] = acc1[r] + bv1;
        }
    }
}

extern "C" void kernel_launch(void* const* d_in, const int* in_sizes, int n_in,
                              void* d_out, int out_size, void* d_ws, size_t ws_size,
                              hipStream_t stream) {
    const float* feats = (const float*)d_in[0];
    const float* ipos  = (const float*)d_in[1];
    const float* opos  = (const float*)d_in[2];
    const float* vsp   = (const float*)d_in[3];
    const float* W     = (const float*)d_in[4];
    const float* bias  = (const float*)d_in[5];

    int N = in_sizes[0] / 64;
    int M = out_size / 64;

    // workspace: imap | omap | ikey | okey | Wt   (no clearing required)
    int*    imap = (int*)d_ws;
    int*    omap = imap + NROWS;
    int*    ikey = omap + NROWS;
    int*    okey = ikey + N;
    __bf16* Wt   = (__bf16*)(okey + M);

    int total = N + M + 27*64*64;
    prep_kernel<<<(total + 255) / 256, 256, 0, stream>>>(ipos, N, opos, M, vsp, W,
                                                         imap, ikey, omap, okey, Wt);
    conv_kernel<<<8 * SLAB, 256, 0, stream>>>(feats, Wt, bias, imap, ikey, omap, okey,
                                              (float*)d_out, N, M);
}